// Round 8
// baseline (310.405 us; speedup 1.0000x reference)
//
#include <hip/hip_runtime.h>
#include <math.h>

#define NN   10000
#define EE   200000
#define RR   400000
#define FIN  128
#define FOUT 64
#define NK   10048           // 157*64, K padded for seqT

#define HASH_BITS 20
#define HSIZE (1u << HASH_BITS)
#define HMASK (HSIZE - 1u)
#define ROWCAP 256           // per-row edge slots (Binomial(400K,1e-4): P(>256)~0)

typedef __bf16 bf16x8 __attribute__((ext_vector_type(8)));
typedef float  f32x4  __attribute__((ext_vector_type(4)));

// ---- workspace layout (units of 4 bytes) ----
#define O_SUMS   0
#define O_CNTS   (O_SUMS + EE)
#define O_ROWCNT (O_CNTS + EE)             // int[NN]
#define O_HKEY   (O_ROWCNT + NN)
#define O_HPRIO  (O_HKEY + HSIZE)
#define O_SEQT   (O_HPRIO + HSIZE)         // bf16[64][NK] (pad cols must be 0)
#define ZERO_WORDS (O_SEQT + (FOUT * NK) / 2)   // div by 4
#define O_SEQ    ZERO_WORDS                // f32[NN][64]
#define O_NUMP   (O_SEQ + NN * FOUT)       // f32[8][NN][64] partials
#define O_SP     (O_NUMP + 8 * NN * FOUT)  // f32[8][NN]
#define O_PAIRS  (O_SP + 8 * NN)           // uint2[NN][ROWCAP]

// ---------------- wide zero fill ----------------
__global__ __launch_bounds__(256) void k_zero(f32x4* __restrict__ p, int n4) {
    int gid = blockIdx.x * 256 + threadIdx.x;
    if (gid < n4) p[gid] = (f32x4){0.f, 0.f, 0.f, 0.f};
}

// ---------------- seq_fts = x @ W^T  (also emits bf16 transposed copy) ----
__global__ __launch_bounds__(256) void k_seqfts(const float* __restrict__ x,
                                                const float* __restrict__ W,
                                                float* __restrict__ seq,
                                                __bf16* __restrict__ seqT) {
    __shared__ float Wt[FIN][FOUT + 1];
    __shared__ float xs[FIN][16 + 1];
    int t = threadIdx.x;
    for (int e = t; e < FOUT * FIN; e += 256) {
        int c = e >> 7, k = e & 127;
        Wt[k][c] = W[e];
    }
    int row0 = blockIdx.x * 16;
    for (int e = t; e < 16 * FIN; e += 256) {
        int r = e >> 7, k = e & 127;
        int gr = row0 + r;
        xs[k][r] = (gr < NN) ? x[(size_t)gr * FIN + k] : 0.f;
    }
    __syncthreads();
    int col = t & 63;
    int rg  = t >> 6;
    float acc[4] = {0.f, 0.f, 0.f, 0.f};
    for (int k = 0; k < FIN; ++k) {
        float w = Wt[k][col];
        #pragma unroll
        for (int i = 0; i < 4; ++i) acc[i] += w * xs[k][rg * 4 + i];
    }
    #pragma unroll
    for (int i = 0; i < 4; ++i) {
        int gr = row0 + rg * 4 + i;
        if (gr < NN) {
            seq[(size_t)gr * FOUT + col] = acc[i];
            seqT[(size_t)col * NK + gr] = (__bf16)acc[i];
        }
    }
}

// ---------------- helpers ----------------
__device__ __forceinline__ unsigned hash_cell(unsigned cell) {
    return (cell * 2654435761u) >> (32 - HASH_BITS);
}
__device__ __forceinline__ void entry_ij(const int* ep, int e, int& i, int& j, int& k) {
    k = (e < EE) ? e : e - EE;
    int a = ep[2 * k], b = ep[2 * k + 1];
    if (e < EE) { i = a; j = b; } else { i = b; j = a; }
}

// ------- merged (wave-level roles, NO LDS, NO barriers):
//         main matmul (reg fragments) || rel segsum || hash build -----------
#define BK 64
#define KSPLIT 8
#define NCHUNK 157
#define CPK 20                           // ceil(157/8)
#define NSTRIP (NN / 16)                 // 625
#define MAINW (NSTRIP * KSPLIT)          // 5000
#define RELW  (RR / 16)                  // 25000 (16 rows per wave)
#define HASHW ((2 * EE + 63) / 64)       // 6250
#define TOTW  (MAINW + RELW + HASHW)     // 36250
#define GRID_MR ((TOTW + 3) / 4)         // 9063 blocks x 4 waves

__global__ __launch_bounds__(256, 4) void k_mainrel(const float* __restrict__ adj,
                                                    const __bf16* __restrict__ seqT,
                                                    const float* __restrict__ rel,
                                                    const float* __restrict__ wrel,
                                                    const int* __restrict__ rseg,
                                                    const int* __restrict__ ep,
                                                    float* __restrict__ sums,
                                                    float* __restrict__ cnts,
                                                    unsigned* __restrict__ hkey,
                                                    unsigned* __restrict__ hprio,
                                                    float* __restrict__ Nump,
                                                    float* __restrict__ Sp) {
    int t   = threadIdx.x;
    int wid = blockIdx.x * 4 + (t >> 6);
    int l   = t & 63;

    if (wid < MAINW) {
        // ---- main role: one wave owns 16 rows x 64 cols, K-slice of 20 chunks.
        // A-frag loaded straight from adj (lane: row=l&15, k=(l>>4)*8+0..7),
        // exp()+bf16-pack in registers; B-frag read from L2-resident seqT.
        int strip = wid % NSTRIP;
        int ks    = wid / NSTRIP;
        int row0  = strip * 16;
        int c0 = ks * CPK, c1 = min(NCHUNK, c0 + CPK);
        int lr = l & 15, lk = l >> 4;
        const float*  arow  = adj  + (size_t)(row0 + lr) * NN;
        const __bf16* bbase = seqT + (size_t)lr * NK;

        f32x4 acc[4];
        #pragma unroll
        for (int n = 0; n < 4; ++n) acc[n] = (f32x4){0.f, 0.f, 0.f, 0.f};
        float rs = 0.f;

        for (int ch = c0; ch < c1; ++ch) {
            int k0 = ch * BK;
            #pragma unroll
            for (int h = 0; h < 2; ++h) {
                int gk = k0 + h * 32 + lk * 8;
                // gk%8==0, NN%8==0 -> gk<NN implies all 8 in bounds
                f32x4 a0 = (f32x4){-1e9f, -1e9f, -1e9f, -1e9f};
                f32x4 a1 = a0;
                if (gk < NN) {
                    a0 = *(const f32x4*)(arow + gk);
                    a1 = *(const f32x4*)(arow + gk + 4);
                }
                float w0 = __expf(a0.x + 0.5f);   // exp(-1e9) -> 0 for OOB
                float w1 = __expf(a0.y + 0.5f);
                float w2 = __expf(a0.z + 0.5f);
                float w3 = __expf(a0.w + 0.5f);
                float w4 = __expf(a1.x + 0.5f);
                float w5 = __expf(a1.y + 0.5f);
                float w6 = __expf(a1.z + 0.5f);
                float w7 = __expf(a1.w + 0.5f);
                rs += ((w0 + w1) + (w2 + w3)) + ((w4 + w5) + (w6 + w7));
                bf16x8 af = { (__bf16)w0, (__bf16)w1, (__bf16)w2, (__bf16)w3,
                              (__bf16)w4, (__bf16)w5, (__bf16)w6, (__bf16)w7 };
                const __bf16* bp = bbase + gk;
                #pragma unroll
                for (int n = 0; n < 4; ++n) {
                    bf16x8 b = *(const bf16x8*)(bp + (size_t)n * 16 * NK);
                    acc[n] = __builtin_amdgcn_mfma_f32_16x16x32_bf16(af, b, acc[n], 0, 0, 0);
                }
            }
        }
        // row-sum: combine the 4 k-subgroups holding the same row
        rs += __shfl_xor(rs, 16, 64);
        rs += __shfl_xor(rs, 32, 64);
        if (lk == 0) Sp[(size_t)ks * NN + row0 + lr] = rs;
        // C/D layout: col = lane&15, row = (lane>>4)*4 + reg
        float* nout = Nump + (size_t)ks * NN * FOUT;
        #pragma unroll
        for (int n = 0; n < 4; ++n) {
            #pragma unroll
            for (int r = 0; r < 4; ++r)
                nout[(size_t)(row0 + lk * 4 + r) * FOUT + n * 16 + lr] = acc[n][r];
        }
        return;
    }

    if (wid < MAINW + RELW) {
        // ---- rel role: 16 rows per wave, 32-lane group per row ----
        int rw   = wid - MAINW;
        int lane = l & 31;
        int half = l >> 5;
        f32x4 wv = *(const f32x4*)(wrel + lane * 4);
        #pragma unroll
        for (int it = 0; it < 8; ++it) {
            int row = rw * 16 + it * 2 + half;   // RELW*16 == RR exactly
            f32x4 v = *(const f32x4*)(rel + (size_t)row * FIN + lane * 4);
            float s = v.x * wv.x + v.y * wv.y + v.z * wv.z + v.w * wv.w;
            #pragma unroll
            for (int off = 16; off >= 1; off >>= 1) s += __shfl_xor(s, off, 64);
            if (lane == 0) {
                int seg = rseg[row];
                atomicAdd(&sums[seg], s);
                atomicAdd(&cnts[seg], 1.0f);
            }
        }
        return;
    }

    // ---- hash-build role ----
    {
        int e = (wid - MAINW - RELW) * 64 + l;
        if (e >= 2 * EE) return;
        int i, j, k;
        entry_ij(ep, e, i, j, k);
        unsigned cell = (unsigned)i * NN + (unsigned)j;
        unsigned keyv = cell + 1u;
        unsigned h = hash_cell(cell);
        while (true) {
            unsigned old = atomicCAS(&hkey[h], 0u, keyv);
            if (old == 0u || old == keyv) break;
            h = (h + 1u) & HMASK;
        }
        atomicMax(&hprio[h], (unsigned)(e + 1));
    }
}

// ------- scatB: winner check + dw compute + push (j,dw) into row bucket -----
__global__ __launch_bounds__(256) void k_scatB(const int* __restrict__ ep,
                                               const float* __restrict__ sums,
                                               const float* __restrict__ cnts,
                                               const unsigned* __restrict__ hkey,
                                               const unsigned* __restrict__ hprio,
                                               const float* __restrict__ adj,
                                               int* __restrict__ rowcnt,
                                               uint2* __restrict__ pairs) {
    int e = blockIdx.x * 256 + threadIdx.x;
    if (e >= 2 * EE) return;
    int i, j, k;
    entry_ij(ep, e, i, j, k);
    unsigned cell = (unsigned)i * NN + (unsigned)j;
    unsigned keyv = cell + 1u;
    unsigned h = hash_cell(cell);
    while (hkey[h] != keyv) h = (h + 1u) & HMASK;
    if (hprio[h] == (unsigned)(e + 1)) {   // last-write-wins winner
        float v   = sums[k] / fmaxf(cnts[k], 1.0f);
        float sg  = 1.f / (1.f + __expf(-v));
        float aij = adj[(size_t)i * NN + j];
        float dw  = __expf(aij + sg) - __expf(aij + 0.5f);
        if (dw != 0.f) {
            int pos = atomicAdd(&rowcnt[i], 1);
            if (pos < ROWCAP)
                pairs[(size_t)i * ROWCAP + pos] =
                    make_uint2((unsigned)j, __float_as_uint(dw));
        }
    }
}

// ------- rowupd: one wave per row: sum partials + edge corr + elu -> out ----
__global__ __launch_bounds__(256) void k_rowupd(const float* __restrict__ Nump,
                                                const float* __restrict__ Sp,
                                                const int* __restrict__ rowcnt,
                                                const uint2* __restrict__ pairs,
                                                const float* __restrict__ seq,
                                                const float* __restrict__ bias,
                                                float* __restrict__ out) {
    int t = threadIdx.x;
    int i = blockIdx.x * 4 + (t >> 6);
    if (i >= NN) return;
    int c = t & 63;
    float acc = 0.f, sb = 0.f;
    #pragma unroll
    for (int ks = 0; ks < 8; ++ks) {
        acc += Nump[(size_t)ks * NN * FOUT + (size_t)i * FOUT + c];
        sb  += Sp[(size_t)ks * NN + i];
    }
    int cnt = min(rowcnt[i], ROWCAP);
    float sdw = 0.f;
    const uint2* pr = pairs + (size_t)i * ROWCAP;
    #pragma unroll 4
    for (int e = 0; e < cnt; ++e) {
        uint2 pk = pr[e];                      // wave-uniform broadcast load
        float d  = __uint_as_float(pk.y);
        acc += d * seq[(size_t)pk.x * FOUT + c];
        sdw += d;
    }
    float v = acc / (sb + sdw) + bias[c];
    out[(size_t)i * FOUT + c] = (v > 0.f) ? v : expm1f(v);
}

extern "C" void kernel_launch(void* const* d_in, const int* in_sizes, int n_in,
                              void* d_out, int out_size, void* d_ws, size_t ws_size,
                              hipStream_t stream) {
    const float* x    = (const float*)d_in[0];
    const float* rel  = (const float*)d_in[1];
    const float* adj  = (const float*)d_in[2];
    const int*   ep   = (const int*)d_in[3];
    const int*   rseg = (const int*)d_in[4];
    const float* W    = (const float*)d_in[5];
    const float* wrel = (const float*)d_in[6];
    const float* bias = (const float*)d_in[7];
    float* out = (float*)d_out;

    float* ws = (float*)d_ws;
    float*    sums   = ws + O_SUMS;
    float*    cnts   = ws + O_CNTS;
    int*      rowcnt = (int*)(ws + O_ROWCNT);
    unsigned* hkey   = (unsigned*)(ws + O_HKEY);
    unsigned* hprio  = (unsigned*)(ws + O_HPRIO);
    __bf16*   seqT   = (__bf16*)(ws + O_SEQT);
    float*    seq    = ws + O_SEQ;
    float*    Nump   = ws + O_NUMP;
    float*    Sp     = ws + O_SP;
    uint2*    pairs  = (uint2*)(ws + O_PAIRS);

    int n4 = ZERO_WORDS / 4;
    k_zero<<<(n4 + 255) / 256, 256, 0, stream>>>((f32x4*)d_ws, n4);
    k_seqfts<<<NN / 16, 256, 0, stream>>>(x, W, seq, seqT);
    k_mainrel<<<GRID_MR, 256, 0, stream>>>(adj, seqT, rel, wrel, rseg, ep,
                                           sums, cnts, hkey, hprio, Nump, Sp);
    k_scatB<<<(2 * EE + 255) / 256, 256, 0, stream>>>(ep, sums, cnts, hkey, hprio,
                                                      adj, rowcnt, pairs);
    k_rowupd<<<(NN + 3) / 4, 256, 0, stream>>>(Nump, Sp, rowcnt, pairs,
                                               seq, bias, out);
}